// Round 10
// baseline (247.415 us; speedup 1.0000x reference)
//
#include <hip/hip_runtime.h>

namespace {

constexpr int B = 32, T = 4096, D = 128;
constexpr float NEG_FILL = -1e30f;
constexpr float ALPHA = 0.5f;
constexpr int CHUNK_ROWS = 64;               // rows of T per block
constexpr int CHUNKS = T / CHUNK_ROWS;       // 64
constexpr int GRID = B * CHUNKS;             // 2048 blocks
constexpr int THREADS = 256;
constexpr int ITERS = CHUNK_ROWS * D / (THREADS * 4);  // 8 -> 16 NT loads in flight
constexpr int NKEYS = 4 * B * D;             // 16384

typedef float vfloat4 __attribute__((ext_vector_type(4)));  // nontemporal-compatible

// Monotone float<->uint mapping; we store ~encf(x) so unsigned atomicMin == float max
// and the identity element is 0xFFFFFFFF (memset-able with 0xFF).
__device__ __forceinline__ unsigned encf(float x) {
  unsigned b = __float_as_uint(x);
  return (b & 0x80000000u) ? ~b : (b | 0x80000000u);
}
__device__ __forceinline__ float decf(unsigned k) {
  unsigned b = (k & 0x80000000u) ? (k ^ 0x80000000u) : ~k;
  return __uint_as_float(b);
}

__global__ __launch_bounds__(THREADS, 4) void seg_kernel(
    const float* __restrict__ outp, const float* __restrict__ labp,
    const int* __restrict__ lens, unsigned* __restrict__ keys,
    float* __restrict__ bsum, unsigned* __restrict__ counter,
    float* __restrict__ res) {
  const int blk = blockIdx.x;
  const int b = blk >> 6;                    // blk / CHUNKS
  const int chunk = blk & (CHUNKS - 1);
  const int Li = lens[b];
  const int half = Li >> 1;
  const int row0 = chunk * CHUNK_ROWS;
  const int t = threadIdx.x;
  const int col = (t * 4) & (D - 1);
  const int rbase = row0 + (t >> 5);         // row of this thread at iter 0
  const size_t base = ((size_t)b * T + (size_t)row0) * (size_t)D + (size_t)(t * 4);

  // ---- issue ALL 16 loads first, nontemporal; sched_barrier pins the cluster ----
  vfloat4 o[ITERS], l[ITERS];
#pragma unroll
  for (int i = 0; i < ITERS; ++i) {
    o[i] = __builtin_nontemporal_load((const vfloat4*)(outp + base + (size_t)i * (THREADS * 4)));
    l[i] = __builtin_nontemporal_load((const vfloat4*)(labp + base + (size_t)i * (THREADS * 4)));
  }
  // R8 evidence: without this the scheduler re-fuses load/consume (~2 outstanding).
  __builtin_amdgcn_sched_barrier(0);

  // ---- sumsq ----
  float s = 0.0f;
#pragma unroll
  for (int i = 0; i < ITERS; ++i) {
    float dx;
    dx = o[i].x - l[i].x; s = fmaf(dx, dx, s);
    dx = o[i].y - l[i].y; s = fmaf(dx, dx, s);
    dx = o[i].z - l[i].z; s = fmaf(dx, dx, s);
    dx = o[i].w - l[i].w; s = fmaf(dx, dx, s);
  }

  // ---- segment maxima (skip entirely if chunk outside both segments) ----
  const bool need1 = row0 < half;                                  // cat 0,1
  const bool need2 = (row0 < Li) && (row0 + CHUNK_ROWS > half);    // cat 2,3
  __shared__ float sh[4][8][D];              // 16 KiB

  if (need1 | need2) {                       // block-uniform
    vfloat4 mO1 = {NEG_FILL, NEG_FILL, NEG_FILL, NEG_FILL};
    vfloat4 mL1 = mO1, mO2 = mO1, mL2 = mO1;
#pragma unroll
    for (int i = 0; i < ITERS; ++i) {
      const int pos = rbase + 8 * i;         // stride 1024 floats = 8 rows
      const bool f1 = pos < half;
      const bool f2 = (pos >= half) & (pos < Li);
      mO1.x = fmaxf(mO1.x, f1 ? o[i].x : NEG_FILL);
      mO1.y = fmaxf(mO1.y, f1 ? o[i].y : NEG_FILL);
      mO1.z = fmaxf(mO1.z, f1 ? o[i].z : NEG_FILL);
      mO1.w = fmaxf(mO1.w, f1 ? o[i].w : NEG_FILL);
      mL1.x = fmaxf(mL1.x, f1 ? l[i].x : NEG_FILL);
      mL1.y = fmaxf(mL1.y, f1 ? l[i].y : NEG_FILL);
      mL1.z = fmaxf(mL1.z, f1 ? l[i].z : NEG_FILL);
      mL1.w = fmaxf(mL1.w, f1 ? l[i].w : NEG_FILL);
      mO2.x = fmaxf(mO2.x, f2 ? o[i].x : NEG_FILL);
      mO2.y = fmaxf(mO2.y, f2 ? o[i].y : NEG_FILL);
      mO2.z = fmaxf(mO2.z, f2 ? o[i].z : NEG_FILL);
      mO2.w = fmaxf(mO2.w, f2 ? o[i].w : NEG_FILL);
      mL2.x = fmaxf(mL2.x, f2 ? l[i].x : NEG_FILL);
      mL2.y = fmaxf(mL2.y, f2 ? l[i].y : NEG_FILL);
      mL2.z = fmaxf(mL2.z, f2 ? l[i].z : NEG_FILL);
      mL2.w = fmaxf(mL2.w, f2 ? l[i].w : NEG_FILL);
    }
    const int r = t >> 5;                    // 0..7
    *(vfloat4*)&sh[0][r][col] = mO1;
    *(vfloat4*)&sh[1][r][col] = mL1;
    *(vfloat4*)&sh[2][r][col] = mO2;
    *(vfloat4*)&sh[3][r][col] = mL2;
    __syncthreads();

    if (t < D) {
      const int c0 = need1 ? 0 : 2;
      const int c1 = need2 ? 4 : 2;
#pragma unroll 4
      for (int c = c0; c < c1; ++c) {
        float m = sh[c][0][t];
#pragma unroll
        for (int r2 = 1; r2 < 8; ++r2) m = fmaxf(m, sh[c][r2][t]);
        atomicMin(&keys[c * B * D + b * D + t], ~encf(m));  // identity = 0xFFFFFFFF
      }
    }
  }

  // ---- block reduction of sumsq -> per-block slot ----
  for (int off = 32; off > 0; off >>= 1) s += __shfl_down(s, off, 64);
  __shared__ float swave[4];
  __shared__ unsigned is_last;
  if ((t & 63) == 0) swave[t >> 6] = s;
  __syncthreads();                           // all block work (incl. key atomics) drained
  if (t == 0) {
    const float tot = swave[0] + swave[1] + swave[2] + swave[3];
    __hip_atomic_store(&bsum[blk], tot, __ATOMIC_RELAXED, __HIP_MEMORY_SCOPE_AGENT);
    __threadfence();                         // device-scope: publish before counting
    // counter memset to 0xFFFFFFFF; the k-th adder sees old = k-2 (mod 2^32),
    // so the LAST (2048th) uniquely sees GRID-2.
    const unsigned old = atomicAdd(counter, 1u);
    is_last = (old == (unsigned)(GRID - 2)) ? 1u : 0u;
  }
  __syncthreads();
  if (!is_last) return;

  // ---- final reduction, performed by the last-finishing block ----
  __threadfence();
  float lf = 0.0f, ls = 0.0f;
#pragma unroll 4
  for (int j = 0; j < 16; ++j) {
    const int rem = t + 256 * j;             // 0..4095 = b*D+d
    const int b2 = rem >> 7;
    if (lens[b2] >= 2) {                     // untouched keys decode to NaN: guard
      const unsigned k0 = __hip_atomic_load(&keys[0 * B * D + rem], __ATOMIC_RELAXED, __HIP_MEMORY_SCOPE_AGENT);
      const unsigned k1 = __hip_atomic_load(&keys[1 * B * D + rem], __ATOMIC_RELAXED, __HIP_MEMORY_SCOPE_AGENT);
      const unsigned k2 = __hip_atomic_load(&keys[2 * B * D + rem], __ATOMIC_RELAXED, __HIP_MEMORY_SCOPE_AGENT);
      const unsigned k3 = __hip_atomic_load(&keys[3 * B * D + rem], __ATOMIC_RELAXED, __HIP_MEMORY_SCOPE_AGENT);
      float d;
      d = decf(~k0) - decf(~k1); lf = fmaf(d, d, lf);
      d = decf(~k2) - decf(~k3); ls = fmaf(d, d, ls);
    }
  }
  float sb = 0.0f;
#pragma unroll 4
  for (int j = 0; j < GRID / 256; ++j)
    sb += __hip_atomic_load(&bsum[t + 256 * j], __ATOMIC_RELAXED, __HIP_MEMORY_SCOPE_AGENT);

  for (int off = 32; off > 0; off >>= 1) {
    sb += __shfl_down(sb, off, 64);
    lf += __shfl_down(lf, off, 64);
    ls += __shfl_down(ls, off, 64);
  }
  __shared__ float rb[4], rf[4], rs[4];
  if ((t & 63) == 0) { rb[t >> 6] = sb; rf[t >> 6] = lf; rs[t >> 6] = ls; }
  __syncthreads();
  if (t == 0) {
    const float S = rb[0] + rb[1] + rb[2] + rb[3];
    const float LF = rf[0] + rf[1] + rf[2] + rf[3];
    const float LS = rs[0] + rs[1] + rs[2] + rs[3];
    const float base = S / ((float)B * (float)T * (float)D);
    res[0] = base + ALPHA * (LF + LS) / ((float)B * (float)D);
  }
}

}  // namespace

extern "C" void kernel_launch(void* const* d_in, const int* in_sizes, int n_in,
                              void* d_out, int out_size, void* d_ws, size_t ws_size,
                              hipStream_t stream) {
  const float* outputs = (const float*)d_in[0];
  const float* labels = (const float*)d_in[1];
  const int* lengths = (const int*)d_in[2];   // harness delivers integers as int32

  unsigned* keys = (unsigned*)d_ws;                       // NKEYS u32
  unsigned* counter = keys + NKEYS;                       // 1 u32
  float* bsum = (float*)(keys + NKEYS + 2);               // GRID floats, 8B-aligned

  // One memset node inits keys (atomicMin identity) AND counter to 0xFFFFFFFF.
  hipMemsetAsync(d_ws, 0xFF, (size_t)(NKEYS + 1) * sizeof(unsigned), stream);
  seg_kernel<<<GRID, THREADS, 0, stream>>>(outputs, labels, lengths, keys, bsum,
                                           counter, (float*)d_out);
}

// Round 11
// 141.737 us; speedup vs baseline: 1.7456x; 1.7456x over previous
//
#include <hip/hip_runtime.h>

namespace {

constexpr int B = 32, T = 4096, D = 128;
constexpr float NEG_FILL = -1e30f;
constexpr float ALPHA = 0.5f;
constexpr int CHUNK_ROWS = 64;               // rows of T per block
constexpr int CHUNKS = T / CHUNK_ROWS;       // 64
constexpr int GRID = B * CHUNKS;             // 2048 blocks
constexpr int THREADS = 256;
constexpr int ITERS = CHUNK_ROWS * D / (THREADS * 4);  // 8 -> 16 NT loads in flight
constexpr int NKEYS = 4 * B * D;             // 16384

typedef float vfloat4 __attribute__((ext_vector_type(4)));  // nontemporal-compatible
typedef float vfloat2 __attribute__((ext_vector_type(2)));

// Monotone float<->uint mapping. We store ~encf(x) and use unsigned atomicMin,
// so the identity element is 0xFFFFFFFF -> initializable by hipMemsetAsync(0xFF)
// (no init kernel). Kernel boundaries provide ordering; NO fences (R10 lesson:
// per-block __threadfence crushed seg_kernel 30->132 us).
__device__ __forceinline__ unsigned encf(float x) {
  unsigned b = __float_as_uint(x);
  return (b & 0x80000000u) ? ~b : (b | 0x80000000u);
}
__device__ __forceinline__ float decf(unsigned k) {
  unsigned b = (k & 0x80000000u) ? (k ^ 0x80000000u) : ~k;
  return __uint_as_float(b);
}

__global__ __launch_bounds__(THREADS, 4) void seg_kernel(
    const float* __restrict__ outp, const float* __restrict__ labp,
    const int* __restrict__ lens, unsigned* __restrict__ keys,
    float* __restrict__ bsum) {
  const int blk = blockIdx.x;
  const int b = blk >> 6;                    // blk / CHUNKS
  const int chunk = blk & (CHUNKS - 1);
  const int Li = lens[b];
  const int half = Li >> 1;
  const int row0 = chunk * CHUNK_ROWS;
  const int t = threadIdx.x;
  const int col = (t * 4) & (D - 1);
  const int rbase = row0 + (t >> 5);         // row of this thread at iter 0
  const size_t base = ((size_t)b * T + (size_t)row0) * (size_t)D + (size_t)(t * 4);

  // ---- issue ALL 16 loads first, nontemporal; sched_barrier pins the cluster ----
  vfloat4 o[ITERS], l[ITERS];
#pragma unroll
  for (int i = 0; i < ITERS; ++i) {
    o[i] = __builtin_nontemporal_load((const vfloat4*)(outp + base + (size_t)i * (THREADS * 4)));
    l[i] = __builtin_nontemporal_load((const vfloat4*)(labp + base + (size_t)i * (THREADS * 4)));
  }
  // R8 evidence: without this the scheduler re-fuses load/consume (~2 outstanding).
  __builtin_amdgcn_sched_barrier(0);

  // ---- sumsq ----
  float s = 0.0f;
#pragma unroll
  for (int i = 0; i < ITERS; ++i) {
    float dx;
    dx = o[i].x - l[i].x; s = fmaf(dx, dx, s);
    dx = o[i].y - l[i].y; s = fmaf(dx, dx, s);
    dx = o[i].z - l[i].z; s = fmaf(dx, dx, s);
    dx = o[i].w - l[i].w; s = fmaf(dx, dx, s);
  }

  // ---- segment maxima (skip entirely if chunk outside both segments) ----
  const bool need1 = row0 < half;                                  // cat 0,1
  const bool need2 = (row0 < Li) && (row0 + CHUNK_ROWS > half);    // cat 2,3
  __shared__ float sh[4][8][D];              // 16 KiB

  if (need1 | need2) {                       // block-uniform
    vfloat4 mO1 = {NEG_FILL, NEG_FILL, NEG_FILL, NEG_FILL};
    vfloat4 mL1 = mO1, mO2 = mO1, mL2 = mO1;
#pragma unroll
    for (int i = 0; i < ITERS; ++i) {
      const int pos = rbase + 8 * i;         // stride 1024 floats = 8 rows
      const bool f1 = pos < half;
      const bool f2 = (pos >= half) & (pos < Li);
      mO1.x = fmaxf(mO1.x, f1 ? o[i].x : NEG_FILL);
      mO1.y = fmaxf(mO1.y, f1 ? o[i].y : NEG_FILL);
      mO1.z = fmaxf(mO1.z, f1 ? o[i].z : NEG_FILL);
      mO1.w = fmaxf(mO1.w, f1 ? o[i].w : NEG_FILL);
      mL1.x = fmaxf(mL1.x, f1 ? l[i].x : NEG_FILL);
      mL1.y = fmaxf(mL1.y, f1 ? l[i].y : NEG_FILL);
      mL1.z = fmaxf(mL1.z, f1 ? l[i].z : NEG_FILL);
      mL1.w = fmaxf(mL1.w, f1 ? l[i].w : NEG_FILL);
      mO2.x = fmaxf(mO2.x, f2 ? o[i].x : NEG_FILL);
      mO2.y = fmaxf(mO2.y, f2 ? o[i].y : NEG_FILL);
      mO2.z = fmaxf(mO2.z, f2 ? o[i].z : NEG_FILL);
      mO2.w = fmaxf(mO2.w, f2 ? o[i].w : NEG_FILL);
      mL2.x = fmaxf(mL2.x, f2 ? l[i].x : NEG_FILL);
      mL2.y = fmaxf(mL2.y, f2 ? l[i].y : NEG_FILL);
      mL2.z = fmaxf(mL2.z, f2 ? l[i].z : NEG_FILL);
      mL2.w = fmaxf(mL2.w, f2 ? l[i].w : NEG_FILL);
    }
    const int r = t >> 5;                    // 0..7
    *(vfloat4*)&sh[0][r][col] = mO1;
    *(vfloat4*)&sh[1][r][col] = mL1;
    *(vfloat4*)&sh[2][r][col] = mO2;
    *(vfloat4*)&sh[3][r][col] = mL2;
    __syncthreads();

    if (t < D) {
      const int c0 = need1 ? 0 : 2;
      const int c1 = need2 ? 4 : 2;
#pragma unroll 4
      for (int c = c0; c < c1; ++c) {
        float m = sh[c][0][t];
#pragma unroll
        for (int r2 = 1; r2 < 8; ++r2) m = fmaxf(m, sh[c][r2][t]);
        atomicMin(&keys[c * B * D + b * D + t], ~encf(m));  // identity = 0xFFFFFFFF
      }
    }
  }

  // ---- block reduction of sumsq -> per-block slot (no atomic, no init) ----
  for (int off = 32; off > 0; off >>= 1) s += __shfl_down(s, off, 64);
  __shared__ float swave[4];
  if ((t & 63) == 0) swave[t >> 6] = s;
  __syncthreads();
  if (t == 0) bsum[blk] = swave[0] + swave[1] + swave[2] + swave[3];
}

// 1024 threads (16 waves on one CU), vectorized reads.
__global__ __launch_bounds__(1024) void final_kernel(
    const unsigned* __restrict__ keys, const float* __restrict__ bsum,
    const int* __restrict__ lens, float* __restrict__ res) {
  const int t = threadIdx.x;                 // 0..1023

  // bsum: 2048 floats -> one float2 per thread
  const vfloat2 bs = *(const vfloat2*)(bsum + 2 * t);
  float s = bs.x + bs.y;

  // keys: 4 cats x 4096 -> one uint4 per cat per thread (i = 4t..4t+3, same b)
  const int i0 = 4 * t;
  const int b = i0 >> 7;
  const float valid = (lens[b] >= 2) ? 1.0f : 0.0f;
  const uint4 k0 = *(const uint4*)(keys + 0 * B * D + i0);
  const uint4 k1 = *(const uint4*)(keys + 1 * B * D + i0);
  const uint4 k2 = *(const uint4*)(keys + 2 * B * D + i0);
  const uint4 k3 = *(const uint4*)(keys + 3 * B * D + i0);
  float lf = 0.0f, ls = 0.0f, d;
  // valid==0 rows may hold untouched keys (decode to NaN under ~enc): multiply
  // per-term by valid BEFORE accumulating would still propagate NaN*0; instead
  // zero the diffs via select on valid.
  if (valid != 0.0f) {
    d = decf(~k0.x) - decf(~k1.x); lf = fmaf(d, d, lf);
    d = decf(~k0.y) - decf(~k1.y); lf = fmaf(d, d, lf);
    d = decf(~k0.z) - decf(~k1.z); lf = fmaf(d, d, lf);
    d = decf(~k0.w) - decf(~k1.w); lf = fmaf(d, d, lf);
    d = decf(~k2.x) - decf(~k3.x); ls = fmaf(d, d, ls);
    d = decf(~k2.y) - decf(~k3.y); ls = fmaf(d, d, ls);
    d = decf(~k2.z) - decf(~k3.z); ls = fmaf(d, d, ls);
    d = decf(~k2.w) - decf(~k3.w); ls = fmaf(d, d, ls);
  }

  for (int off = 32; off > 0; off >>= 1) {
    s += __shfl_down(s, off, 64);
    lf += __shfl_down(lf, off, 64);
    ls += __shfl_down(ls, off, 64);
  }
  __shared__ float sb[16], sf[16], ss[16];
  if ((t & 63) == 0) { sb[t >> 6] = s; sf[t >> 6] = lf; ss[t >> 6] = ls; }
  __syncthreads();
  if (t == 0) {
    float S = 0, LF = 0, LS = 0;
#pragma unroll
    for (int w = 0; w < 16; ++w) { S += sb[w]; LF += sf[w]; LS += ss[w]; }
    const float base = S / ((float)B * (float)T * (float)D);
    res[0] = base + ALPHA * (LF + LS) / ((float)B * (float)D);
  }
}

}  // namespace

extern "C" void kernel_launch(void* const* d_in, const int* in_sizes, int n_in,
                              void* d_out, int out_size, void* d_ws, size_t ws_size,
                              hipStream_t stream) {
  const float* outputs = (const float*)d_in[0];
  const float* labels = (const float*)d_in[1];
  const int* lengths = (const int*)d_in[2];   // harness delivers integers as int32

  unsigned* keys = (unsigned*)d_ws;                       // NKEYS u32
  float* bsum = (float*)(keys + NKEYS);                   // GRID floats

  // One memset node inits keys to the atomicMin identity (0xFFFFFFFF).
  hipMemsetAsync(keys, 0xFF, (size_t)NKEYS * sizeof(unsigned), stream);
  seg_kernel<<<GRID, THREADS, 0, stream>>>(outputs, labels, lengths, keys, bsum);
  final_kernel<<<1, 1024, 0, stream>>>(keys, bsum, lengths, (float*)d_out);
}